// Round 10
// baseline (210.769 us; speedup 1.0000x reference)
//
#include <hip/hip_runtime.h>
#include <cstdint>
#include <cstddef>

#define NTOK 2048
#define DMODEL 1024
#define HD 64
#define MROWS 8192

using f16x8  = __attribute__((ext_vector_type(8))) _Float16;
using f16x4  = __attribute__((ext_vector_type(4))) _Float16;
using f32x4  = __attribute__((ext_vector_type(4))) float;
using f32x16 = __attribute__((ext_vector_type(16))) float;
using u16x8  = __attribute__((ext_vector_type(8))) unsigned short;
using u32x4  = __attribute__((ext_vector_type(4))) unsigned int;

#define Z16 {0.f,0.f,0.f,0.f,0.f,0.f,0.f,0.f,0.f,0.f,0.f,0.f,0.f,0.f,0.f,0.f}

__device__ __forceinline__ unsigned pkf16(float a, float b) {
  return __builtin_bit_cast(unsigned, __builtin_amdgcn_cvt_pkrtz(a, b));
}
__device__ __forceinline__ void plswap(unsigned &a, unsigned &b) {
  auto r = __builtin_amdgcn_permlane32_swap(a, b, false, false);
  a = r[0]; b = r[1];
}
// raw v_exp_f32: args always <= 0; flush-to-zero below -126 is correct for
// softmax tails.
__device__ __forceinline__ float fexp2(float x) {
  return __builtin_amdgcn_exp2f(x);
}

// ---------------------------------------------------------------------------
// f32 -> f16 convert, x (scale=1)
// ---------------------------------------------------------------------------
__global__ __launch_bounds__(256) void cvt_f32_f16(const float* __restrict__ in,
                                                   _Float16* __restrict__ out,
                                                   int n4, float scale) {
  int idx = blockIdx.x * 256 + threadIdx.x;
  if (idx < n4) {
    float4 v = reinterpret_cast<const float4*>(in)[idx];
    f16x4 o;
    o.x = (_Float16)(v.x * scale); o.y = (_Float16)(v.y * scale);
    o.z = (_Float16)(v.z * scale); o.w = (_Float16)(v.w * scale);
    reinterpret_cast<f16x4*>(out)[idx] = o;
  }
}

// both weight matrices in one launch; log2(e) folded into Wq
__global__ __launch_bounds__(256) void cvt_w(const float* __restrict__ Wk,
                                             const float* __restrict__ Wq,
                                             _Float16* __restrict__ Wkb,
                                             _Float16* __restrict__ Wqb) {
  const int idx = blockIdx.x * 256 + threadIdx.x;
  const float* in = blockIdx.y ? Wq : Wk;
  _Float16* out = blockIdx.y ? Wqb : Wkb;
  const float scale = blockIdx.y ? 1.4426950408889634f : 1.0f;
  float4 v = reinterpret_cast<const float4*>(in)[idx];
  f16x4 o;
  o.x = (_Float16)(v.x * scale); o.y = (_Float16)(v.y * scale);
  o.z = (_Float16)(v.z * scale); o.w = (_Float16)(v.w * scale);
  reinterpret_cast<f16x4*>(out)[idx] = o;
}

// ---------------------------------------------------------------------------
// f16 MFMA GEMM: Y[m][o] = sum_k X[m][k] * W[o][k]  (NT), Y stored f16.
// ---------------------------------------------------------------------------
#define GLDS16(g, l) __builtin_amdgcn_global_load_lds(                      \
    (const __attribute__((address_space(1))) void*)(g),                     \
    (__attribute__((address_space(3))) void*)(l), 16, 0, 0)

__global__ __launch_bounds__(256) void gemm_f16(
    const _Float16* __restrict__ X,
    const _Float16* __restrict__ Wk,
    const _Float16* __restrict__ Wq,
    _Float16* __restrict__ Kb,
    _Float16* __restrict__ Qb) {
  const _Float16* __restrict__ W = blockIdx.z ? Wq : Wk;
  _Float16* __restrict__ Y = blockIdx.z ? Qb : Kb;

  __shared__ _Float16 As[2][128 * 32];
  __shared__ _Float16 Bs[2][128 * 32];

  const int tid = threadIdx.x;
  const int lane = tid & 63;
  const int w = tid >> 6;
  const int m0 = blockIdx.x * 128;
  const int o0 = blockIdx.y * 128;

  const int srow = w * 32 + (lane >> 2);
  const int scol = (lane & 3) * 8;
  const _Float16* xsrc = X + (size_t)(m0 + srow) * DMODEL + scol;
  const _Float16* wsrc = W + (size_t)(o0 + srow) * DMODEL + scol;

  const int wr = w >> 1, wc = w & 1;
  const int arow = lane & 15, kg = lane >> 4;

  f32x4 zero = {0.f, 0.f, 0.f, 0.f};
  f32x4 acc[4][4];
#pragma unroll
  for (int mi = 0; mi < 4; ++mi)
#pragma unroll
    for (int ni = 0; ni < 4; ++ni) acc[mi][ni] = zero;

  GLDS16(xsrc,               &As[0][(w * 32) * 32]);
  GLDS16(xsrc + 16 * DMODEL, &As[0][(w * 32 + 16) * 32]);
  GLDS16(wsrc,               &Bs[0][(w * 32) * 32]);
  GLDS16(wsrc + 16 * DMODEL, &Bs[0][(w * 32 + 16) * 32]);

  for (int kt = 0; kt < 32; ++kt) {
    __syncthreads();
    if (kt + 1 < 32) {
      const int ko = (kt + 1) * 32;
      const int bn = (kt + 1) & 1;
      GLDS16(xsrc + ko,               &As[bn][(w * 32) * 32]);
      GLDS16(xsrc + ko + 16 * DMODEL, &As[bn][(w * 32 + 16) * 32]);
      GLDS16(wsrc + ko,               &Bs[bn][(w * 32) * 32]);
      GLDS16(wsrc + ko + 16 * DMODEL, &Bs[bn][(w * 32 + 16) * 32]);
    }
    const int buf = kt & 1;
    f16x8 af[4], bfr[4];
#pragma unroll
    for (int mi = 0; mi < 4; ++mi)
      af[mi] = *reinterpret_cast<const f16x8*>(
          &As[buf][(wr * 64 + mi * 16 + arow) * 32 + kg * 8]);
#pragma unroll
    for (int ni = 0; ni < 4; ++ni)
      bfr[ni] = *reinterpret_cast<const f16x8*>(
          &Bs[buf][(wc * 64 + ni * 16 + arow) * 32 + kg * 8]);
#pragma unroll
    for (int mi = 0; mi < 4; ++mi)
#pragma unroll
      for (int ni = 0; ni < 4; ++ni)
        acc[mi][ni] = __builtin_amdgcn_mfma_f32_16x16x32_f16(
            af[mi], bfr[ni], acc[mi][ni], 0, 0, 0);
  }

#pragma unroll
  for (int mi = 0; mi < 4; ++mi) {
#pragma unroll
    for (int ni = 0; ni < 4; ++ni) {
#pragma unroll
      for (int r = 0; r < 4; ++r) {
        const int m = m0 + wr * 64 + mi * 16 + kg * 4 + r;
        const int o = o0 + wc * 64 + ni * 16 + arow;
        Y[(size_t)m * DMODEL + o] = (_Float16)acc[mi][ni][r];
      }
    }
  }
}

// ---------------------------------------------------------------------------
// Combined pack kernel (grid.y: 0 = pack Q rows, 1 = pack K transposed).
// y=0: Qp[bh][rt(32-row tiles)][ks][lane][8]  = Q_head[rt*32+(l&31)][ks*16+(l>>5)*8+e]
// y=1: KTp[bh][jt][ds][ks][lane][8] = K_head[jt*64+ks*16+(l>>5)*8+e][ds*32+(l&31)]
// ---------------------------------------------------------------------------
__global__ __launch_bounds__(256) void pack_qkt(
    const _Float16* __restrict__ Qb,
    const _Float16* __restrict__ Kb,
    _Float16* __restrict__ Qp,
    _Float16* __restrict__ KTp) {
  const int blk = blockIdx.x;
  const int bh = blk >> 5;
  const int t64 = blk & 31;
  const int b = bh >> 4, h = bh & 15;
  const int tid = threadIdx.x;
  const _Float16* Src = blockIdx.y ? Kb : Qb;

  __shared__ _Float16 t[64][72];
#pragma unroll
  for (int rr = 0; rr < 2; ++rr) {
    const int c = tid + rr * 256;
    const int jr = c >> 3, dcol = (c & 7) * 8;
    *reinterpret_cast<f16x8*>(&t[jr][dcol]) =
        *reinterpret_cast<const f16x8*>(
            &Src[(size_t)(b * NTOK + t64 * 64 + jr) * DMODEL + h * HD + dcol]);
  }
  __syncthreads();
  if (blockIdx.y == 0) {
#pragma unroll
    for (int rr = 0; rr < 2; ++rr) {
      const int cI = tid + rr * 256;   // (rs,ks,l)
      const int rs = cI >> 8, ks = (cI >> 6) & 3, l = cI & 63;
      f16x8 v = *reinterpret_cast<const f16x8*>(
          &t[rs * 32 + (l & 31)][ks * 16 + (l >> 5) * 8]);
      const size_t ch = ((size_t)(bh * 64 + t64 * 2 + rs) * 4 + ks) * 512 + l * 8;
      *reinterpret_cast<f16x8*>(&Qp[ch]) = v;
    }
  } else {
#pragma unroll
    for (int rr = 0; rr < 2; ++rr) {
      const int cI = tid + rr * 256;   // (ds,ks,l)
      const int ds = cI >> 8, ks = (cI >> 6) & 3, l = cI & 63;
      const int col = ds * 32 + (l & 31);
      const int row0 = ks * 16 + (l >> 5) * 8;
      f16x8 v;
#pragma unroll
      for (int e = 0; e < 8; ++e) v[e] = t[row0 + e][col];
      const size_t ch = (((size_t)(bh * 32 + t64) * 2 + ds) * 4 + ks) * 512 + l * 8;
      *reinterpret_cast<f16x8*>(&KTp[ch]) = v;
    }
  }
}

// ---------------------------------------------------------------------------
// Swapped-operand MFMA flash attention, BI=64: each wave owns TWO 32-row
// i-blocks (kbf0/kbf1) and processes 32-j tiles. Q and KT fragment loads are
// shared by both i-blocks -> per-wave operand traffic is amortized 2x
// (512 waves stream 1 GB total instead of 4096 waves streaming 2 GB).
// Per tile: s0 = mfma(Q, K_i0), s1 = mfma(Q, K_i1); per-block in-register
// softmax (defer-max THR=8, per-row rescale routed via per-wave LDS line);
// P repacked in-register (cvt_pkrtz + permlane32_swap, r4-verified chain);
// O(4 quadrants) += mfma(P, KT). All loads lane -> base + lane*16B.
// ---------------------------------------------------------------------------
__global__ __launch_bounds__(256) void attn_mfma(
    const _Float16* __restrict__ Kb,
    const _Float16* __restrict__ Qp,
    const _Float16* __restrict__ KTp,
    float* __restrict__ out) {
  const int bid = blockIdx.x;
  const int myid = (bid & 7) * 64 + (bid >> 3);   // 512 blocks, bijective
  const int bh = myid >> 3;                       // 8 blocks per head
  const int itile = myid & 7;
  const int b = bh >> 4, h = bh & 15;
  const int tid = threadIdx.x, lane = tid & 63, w = tid >> 6;
  const int l31 = lane & 31;
  const int hi = lane >> 5;
  const int hi8 = hi * 8;
  const int i0 = itile * 256 + w * 64;            // wave's first i-row

  const _Float16* Kh   = Kb + (size_t)b * NTOK * DMODEL + h * HD;
  const _Float16* qpp  = Qp  + (size_t)bh * 131072 + lane * 8;
  const _Float16* ktpp = KTp + (size_t)bh * 131072 + lane * 8;

  __shared__ float lsl[4][2][32];
  __shared__ float scl[4][2][32];

  // B-frags of K for the two i-blocks (one-time, uncoalesced but tiny)
  f16x8 kbf0[4], kbf1[4];
#pragma unroll
  for (int ks = 0; ks < 4; ++ks) {
    kbf0[ks] = *reinterpret_cast<const f16x8*>(
        &Kh[(size_t)(i0 + l31) * DMODEL + ks * 16 + hi8]);
    kbf1[ks] = *reinterpret_cast<const f16x8*>(
        &Kh[(size_t)(i0 + 32 + l31) * DMODEL + ks * 16 + hi8]);
  }

  const f32x16 z16v = Z16;
  f32x16 o00 = z16v, o01 = z16v, o10 = z16v, o11 = z16v;
  float m0reg = -1e30f, ls0 = 0.f;
  float m1reg = -1e30f, ls1 = 0.f;

  for (int jt = 0; jt < 64; ++jt) {
    // ---- Q fragments for this 32-j tile (shared by both i-blocks) ----
    f16x8 q[4];
#pragma unroll
    for (int ks = 0; ks < 4; ++ks)
      q[ks] = *reinterpret_cast<const f16x8*>(qpp + ((size_t)jt * 4 + ks) * 512);

    // ---- QK^T for both i-blocks ----
    f32x16 s0 = z16v, s1 = z16v;
    __builtin_amdgcn_s_setprio(1);
#pragma unroll
    for (int ks = 0; ks < 4; ++ks)
      s0 = __builtin_amdgcn_mfma_f32_32x32x16_f16(q[ks], kbf0[ks], s0, 0, 0, 0);
#pragma unroll
    for (int ks = 0; ks < 4; ++ks)
      s1 = __builtin_amdgcn_mfma_f32_32x32x16_f16(q[ks], kbf1[ks], s1, 0, 0, 0);
    __builtin_amdgcn_s_setprio(0);

    // ---- KT fragments (independent of softmax; latency hidden under it) ----
    f16x8 kt0[2], kt1[2];
    {
      const size_t base = ((size_t)(jt >> 1) * 8 + (jt & 1) * 2) * 512;
#pragma unroll
      for (int kk = 0; kk < 2; ++kk) {
        kt0[kk] = *reinterpret_cast<const f16x8*>(ktpp + base + (size_t)kk * 512);
        kt1[kk] = *reinterpret_cast<const f16x8*>(ktpp + base + (size_t)(4 + kk) * 512);
      }
    }

    f16x8 pfr0[2], pfr1[2];

#define SOFTMAX_BLOCK(S, MREG, LS, SCL, PFR)                                  \
    {                                                                         \
      float m0 = fmaxf(S[0], S[4]);                                           \
      float m1 = fmaxf(S[1], S[5]);                                           \
      float m2 = fmaxf(S[2], S[6]);                                           \
      float m3 = fmaxf(S[3], S[7]);                                           \
      _Pragma("unroll")                                                       \
      for (int r = 8; r < 16; r += 4) {                                       \
        m0 = fmaxf(m0, S[r]);                                                 \
        m1 = fmaxf(m1, S[r + 1]);                                             \
        m2 = fmaxf(m2, S[r + 2]);                                             \
        m3 = fmaxf(m3, S[r + 3]);                                             \
      }                                                                       \
      float pm = fmaxf(fmaxf(m0, m1), fmaxf(m2, m3));                         \
      pm = fmaxf(pm, __shfl_xor(pm, 32));                                     \
      if (!__all(pm <= MREG + 8.0f)) {                                        \
        const float mn = fmaxf(MREG, pm);                                     \
        const float sc = fexp2(MREG - mn);                                    \
        LS *= sc;                                                             \
        MREG = mn;                                                            \
        SCL[l31] = sc;                                                        \
        _Pragma("unroll")                                                     \
        for (int r = 0; r < 16; ++r) {                                        \
          const int il = (r & 3) + 8 * (r >> 2) + 4 * hi;                     \
          const float scr = SCL[il];                                          \
          if (&S == &s0) { o00[r] *= scr; o01[r] *= scr; }                    \
          else           { o10[r] *= scr; o11[r] *= scr; }                    \
        }                                                                     \
      }                                                                       \
      float pa[16];                                                           \
      _Pragma("unroll")                                                       \
      for (int r = 0; r < 16; ++r) pa[r] = fexp2(S[r] - MREG);                \
      float l0 = 0.f, l1 = 0.f, l2 = 0.f, l3 = 0.f;                           \
      _Pragma("unroll")                                                       \
      for (int r = 0; r < 16; r += 4) {                                       \
        l0 += pa[r];     l1 += pa[r + 1];                                     \
        l2 += pa[r + 2]; l3 += pa[r + 3];                                     \
      }                                                                       \
      LS += (l0 + l1) + (l2 + l3);                                            \
      unsigned a0 = pkf16(pa[0], pa[1]),  b0 = pkf16(pa[4], pa[5]);           \
      unsigned a1 = pkf16(pa[2], pa[3]),  b1 = pkf16(pa[6], pa[7]);           \
      plswap(a0, b0); plswap(a1, b1);                                         \
      u32x4 t; t[0] = a0; t[1] = a1; t[2] = b0; t[3] = b1;                    \
      PFR[0] = __builtin_bit_cast(f16x8, t);                                  \
      unsigned a2 = pkf16(pa[8], pa[9]),   b2 = pkf16(pa[12], pa[13]);        \
      unsigned a3 = pkf16(pa[10], pa[11]), b3 = pkf16(pa[14], pa[15]);        \
      plswap(a2, b2); plswap(a3, b3);                                         \
      t[0] = a2; t[1] = a3; t[2] = b2; t[3] = b3;                             \
      PFR[1] = __builtin_bit_cast(f16x8, t);                                  \
    }

    SOFTMAX_BLOCK(s0, m0reg, ls0, scl[w][0], pfr0)
    SOFTMAX_BLOCK(s1, m1reg, ls1, scl[w][1], pfr1)
#undef SOFTMAX_BLOCK

    // ---- PV: 4 output quadrants x 2 k-steps ----
    __builtin_amdgcn_s_setprio(1);
#pragma unroll
    for (int kk = 0; kk < 2; ++kk) {
      o00 = __builtin_amdgcn_mfma_f32_32x32x16_f16(pfr0[kk], kt0[kk], o00, 0, 0, 0);
      o01 = __builtin_amdgcn_mfma_f32_32x32x16_f16(pfr0[kk], kt1[kk], o01, 0, 0, 0);
      o10 = __builtin_amdgcn_mfma_f32_32x32x16_f16(pfr1[kk], kt0[kk], o10, 0, 0, 0);
      o11 = __builtin_amdgcn_mfma_f32_32x32x16_f16(pfr1[kk], kt1[kk], o11, 0, 0, 0);
    }
    __builtin_amdgcn_s_setprio(0);
  }

  // ---- finalize: combine lsum halves, divide, store ----
  lsl[w][0][l31] = ls0 + __shfl_xor(ls0, 32);
  lsl[w][1][l31] = ls1 + __shfl_xor(ls1, 32);
#pragma unroll
  for (int r = 0; r < 16; ++r) {
    const int il = (r & 3) + 8 * (r >> 2) + 4 * hi;
    const float inv0 = 1.0f / lsl[w][0][il];
    const float inv1 = 1.0f / lsl[w][1][il];
    const size_t rowb0 = ((size_t)bh * NTOK + i0 + il) * HD;
    const size_t rowb1 = ((size_t)bh * NTOK + i0 + 32 + il) * HD;
    out[rowb0 + l31]      = o00[r] * inv0;
    out[rowb0 + 32 + l31] = o01[r] * inv0;
    out[rowb1 + l31]      = o10[r] * inv1;
    out[rowb1 + 32 + l31] = o11[r] * inv1;
  }
}

extern "C" void kernel_launch(void* const* d_in, const int* in_sizes, int n_in,
                              void* d_out, int out_size, void* d_ws, size_t ws_size,
                              hipStream_t stream) {
  const float* x  = (const float*)d_in[0];
  const float* Wk = (const float*)d_in[1];
  const float* Wq = (const float*)d_in[2];
  // d_in[3] (Wv) is dead code in the reference — never read.
  float* out = (float*)d_out;

  // ws (f16 elems): [xb|Qp: 8388608][Wkb: 1048576][Wqb: 1048576]
  //                 [Kb: 8388608][Qb|KTp: 8388608]
  _Float16* xb  = (_Float16*)d_ws;
  _Float16* Qp  = xb;
  _Float16* Wkb = xb + (size_t)8388608;
  _Float16* Wqb = Wkb + (size_t)1048576;
  _Float16* Kb  = Wqb + (size_t)1048576;
  _Float16* Qb  = Kb + (size_t)8388608;
  _Float16* KTp = Qb;

  cvt_f32_f16<<<8192, 256, 0, stream>>>(x, xb, 2097152, 1.0f);
  cvt_w<<<dim3(1024, 2), 256, 0, stream>>>(Wk, Wq, Wkb, Wqb);

  dim3 ggrid(MROWS / 128, DMODEL / 128, 2);
  gemm_f16<<<ggrid, 256, 0, stream>>>(xb, Wkb, Wqb, Kb, Qb);

  pack_qkt<<<dim3(2048, 2), 256, 0, stream>>>(Qb, Kb, Qp, KTp);

  attn_mfma<<<512, 256, 0, stream>>>(Kb, Qp, KTp, out);
}

// Round 11
// 189.409 us; speedup vs baseline: 1.1128x; 1.1128x over previous
//
#include <hip/hip_runtime.h>
#include <cstdint>
#include <cstddef>

#define NTOK 2048
#define DMODEL 1024
#define HD 64
#define MROWS 8192

using f16x8  = __attribute__((ext_vector_type(8))) _Float16;
using f16x4  = __attribute__((ext_vector_type(4))) _Float16;
using f32x4  = __attribute__((ext_vector_type(4))) float;
using f32x16 = __attribute__((ext_vector_type(16))) float;
using u16x8  = __attribute__((ext_vector_type(8))) unsigned short;
using u32x4  = __attribute__((ext_vector_type(4))) unsigned int;

#define Z16 {0.f,0.f,0.f,0.f,0.f,0.f,0.f,0.f,0.f,0.f,0.f,0.f,0.f,0.f,0.f,0.f}

__device__ __forceinline__ unsigned pkf16(float a, float b) {
  return __builtin_bit_cast(unsigned, __builtin_amdgcn_cvt_pkrtz(a, b));
}
__device__ __forceinline__ void plswap(unsigned &a, unsigned &b) {
  auto r = __builtin_amdgcn_permlane32_swap(a, b, false, false);
  a = r[0]; b = r[1];
}
// raw v_exp_f32: args always <= 0; flush-to-zero below -126 is correct for
// softmax tails.
__device__ __forceinline__ float fexp2(float x) {
  return __builtin_amdgcn_exp2f(x);
}

// ---------------------------------------------------------------------------
// f32 -> f16 convert (x)
// ---------------------------------------------------------------------------
__global__ __launch_bounds__(256) void cvt_f32_f16(const float* __restrict__ in,
                                                   _Float16* __restrict__ out,
                                                   int n4, float scale) {
  int idx = blockIdx.x * 256 + threadIdx.x;
  if (idx < n4) {
    float4 v = reinterpret_cast<const float4*>(in)[idx];
    f16x4 o;
    o.x = (_Float16)(v.x * scale); o.y = (_Float16)(v.y * scale);
    o.z = (_Float16)(v.z * scale); o.w = (_Float16)(v.w * scale);
    reinterpret_cast<f16x4*>(out)[idx] = o;
  }
}

// both weight matrices in one launch; log2(e) folded into Wq
__global__ __launch_bounds__(256) void cvt_w(const float* __restrict__ Wk,
                                             const float* __restrict__ Wq,
                                             _Float16* __restrict__ Wkb,
                                             _Float16* __restrict__ Wqb) {
  const int idx = blockIdx.x * 256 + threadIdx.x;
  const float* in = blockIdx.y ? Wq : Wk;
  _Float16* out = blockIdx.y ? Wqb : Wkb;
  const float scale = blockIdx.y ? 1.4426950408889634f : 1.0f;
  float4 v = reinterpret_cast<const float4*>(in)[idx];
  f16x4 o;
  o.x = (_Float16)(v.x * scale); o.y = (_Float16)(v.y * scale);
  o.z = (_Float16)(v.z * scale); o.w = (_Float16)(v.w * scale);
  reinterpret_cast<f16x4*>(out)[idx] = o;
}

// ---------------------------------------------------------------------------
// f16 MFMA GEMM: Y[m][o] = sum_k X[m][k] * W[o][k]  (NT), Y stored f16.
// ---------------------------------------------------------------------------
#define GLDS16(g, l) __builtin_amdgcn_global_load_lds(                      \
    (const __attribute__((address_space(1))) void*)(g),                     \
    (__attribute__((address_space(3))) void*)(l), 16, 0, 0)

__global__ __launch_bounds__(256) void gemm_f16(
    const _Float16* __restrict__ X,
    const _Float16* __restrict__ Wk,
    const _Float16* __restrict__ Wq,
    _Float16* __restrict__ Kb,
    _Float16* __restrict__ Qb) {
  const _Float16* __restrict__ W = blockIdx.z ? Wq : Wk;
  _Float16* __restrict__ Y = blockIdx.z ? Qb : Kb;

  __shared__ _Float16 As[2][128 * 32];
  __shared__ _Float16 Bs[2][128 * 32];

  const int tid = threadIdx.x;
  const int lane = tid & 63;
  const int w = tid >> 6;
  const int m0 = blockIdx.x * 128;
  const int o0 = blockIdx.y * 128;

  const int srow = w * 32 + (lane >> 2);
  const int scol = (lane & 3) * 8;
  const _Float16* xsrc = X + (size_t)(m0 + srow) * DMODEL + scol;
  const _Float16* wsrc = W + (size_t)(o0 + srow) * DMODEL + scol;

  const int wr = w >> 1, wc = w & 1;
  const int arow = lane & 15, kg = lane >> 4;

  f32x4 zero = {0.f, 0.f, 0.f, 0.f};
  f32x4 acc[4][4];
#pragma unroll
  for (int mi = 0; mi < 4; ++mi)
#pragma unroll
    for (int ni = 0; ni < 4; ++ni) acc[mi][ni] = zero;

  GLDS16(xsrc,               &As[0][(w * 32) * 32]);
  GLDS16(xsrc + 16 * DMODEL, &As[0][(w * 32 + 16) * 32]);
  GLDS16(wsrc,               &Bs[0][(w * 32) * 32]);
  GLDS16(wsrc + 16 * DMODEL, &Bs[0][(w * 32 + 16) * 32]);

  for (int kt = 0; kt < 32; ++kt) {
    __syncthreads();
    if (kt + 1 < 32) {
      const int ko = (kt + 1) * 32;
      const int bn = (kt + 1) & 1;
      GLDS16(xsrc + ko,               &As[bn][(w * 32) * 32]);
      GLDS16(xsrc + ko + 16 * DMODEL, &As[bn][(w * 32 + 16) * 32]);
      GLDS16(wsrc + ko,               &Bs[bn][(w * 32) * 32]);
      GLDS16(wsrc + ko + 16 * DMODEL, &Bs[bn][(w * 32 + 16) * 32]);
    }
    const int buf = kt & 1;
    f16x8 af[4], bfr[4];
#pragma unroll
    for (int mi = 0; mi < 4; ++mi)
      af[mi] = *reinterpret_cast<const f16x8*>(
          &As[buf][(wr * 64 + mi * 16 + arow) * 32 + kg * 8]);
#pragma unroll
    for (int ni = 0; ni < 4; ++ni)
      bfr[ni] = *reinterpret_cast<const f16x8*>(
          &Bs[buf][(wc * 64 + ni * 16 + arow) * 32 + kg * 8]);
#pragma unroll
    for (int mi = 0; mi < 4; ++mi)
#pragma unroll
      for (int ni = 0; ni < 4; ++ni)
        acc[mi][ni] = __builtin_amdgcn_mfma_f32_16x16x32_f16(
            af[mi], bfr[ni], acc[mi][ni], 0, 0, 0);
  }

#pragma unroll
  for (int mi = 0; mi < 4; ++mi) {
#pragma unroll
    for (int ni = 0; ni < 4; ++ni) {
#pragma unroll
      for (int r = 0; r < 4; ++r) {
        const int m = m0 + wr * 64 + mi * 16 + kg * 4 + r;
        const int o = o0 + wc * 64 + ni * 16 + arow;
        Y[(size_t)m * DMODEL + o] = (_Float16)acc[mi][ni][r];
      }
    }
  }
}

// ---------------------------------------------------------------------------
// Combined pack kernel (grid.y: 0 = pack Q rows, 1 = pack K transposed).
// y=0: Qp[bh][rt(32-row tiles)][ks][lane][8]  = Q_head[rt*32+(l&31)][ks*16+(l>>5)*8+e]
// y=1: KTp[bh][jt][ds][ks][lane][8] = K_head[jt*64+ks*16+(l>>5)*8+e][ds*32+(l&31)]
// ---------------------------------------------------------------------------
__global__ __launch_bounds__(256) void pack_qkt(
    const _Float16* __restrict__ Qb,
    const _Float16* __restrict__ Kb,
    _Float16* __restrict__ Qp,
    _Float16* __restrict__ KTp) {
  const int blk = blockIdx.x;
  const int bh = blk >> 5;
  const int t64 = blk & 31;
  const int b = bh >> 4, h = bh & 15;
  const int tid = threadIdx.x;
  const _Float16* Src = blockIdx.y ? Kb : Qb;

  __shared__ _Float16 t[64][72];
#pragma unroll
  for (int rr = 0; rr < 2; ++rr) {
    const int c = tid + rr * 256;
    const int jr = c >> 3, dcol = (c & 7) * 8;
    *reinterpret_cast<f16x8*>(&t[jr][dcol]) =
        *reinterpret_cast<const f16x8*>(
            &Src[(size_t)(b * NTOK + t64 * 64 + jr) * DMODEL + h * HD + dcol]);
  }
  __syncthreads();
  if (blockIdx.y == 0) {
#pragma unroll
    for (int rr = 0; rr < 2; ++rr) {
      const int cI = tid + rr * 256;   // (rs,ks,l)
      const int rs = cI >> 8, ks = (cI >> 6) & 3, l = cI & 63;
      f16x8 v = *reinterpret_cast<const f16x8*>(
          &t[rs * 32 + (l & 31)][ks * 16 + (l >> 5) * 8]);
      const size_t ch = ((size_t)(bh * 64 + t64 * 2 + rs) * 4 + ks) * 512 + l * 8;
      *reinterpret_cast<f16x8*>(&Qp[ch]) = v;
    }
  } else {
#pragma unroll
    for (int rr = 0; rr < 2; ++rr) {
      const int cI = tid + rr * 256;   // (ds,ks,l)
      const int ds = cI >> 8, ks = (cI >> 6) & 3, l = cI & 63;
      const int col = ds * 32 + (l & 31);
      const int row0 = ks * 16 + (l >> 5) * 8;
      f16x8 v;
#pragma unroll
      for (int e = 0; e < 8; ++e) v[e] = t[row0 + e][col];
      const size_t ch = (((size_t)(bh * 32 + t64) * 2 + ds) * 4 + ks) * 512 + l * 8;
      *reinterpret_cast<f16x8*>(&KTp[ch]) = v;
    }
  }
}

// ---------------------------------------------------------------------------
// Swapped-operand MFMA flash attention (r9 structure) + cooperative LDS
// staging: the 4 waves of a block consume IDENTICAL Q/KT fragments, so the
// block stages each 16KB j-tile (8 Q chunks + 8 KT chunks) into LDS ONCE via
// global_load_lds (each wave stages 4 chunks), double-buffered, one barrier
// per tile. Cuts vector-memory traffic 4x (2.1 GB -> 0.53 GB) at unchanged
// wave count (r10 lesson: wave count must stay at 4096).
// Per 64-j tile: s0/s1 = mfma(Q, kbf); in-register softmax (defer-max THR=8,
// per-row rescale via LDS scl line); in-register P repack (cvt_pkrtz +
// permlane32_swap); O += mfma(P, KT). Stores as reference's flat reshape.
// ---------------------------------------------------------------------------
__global__ __launch_bounds__(256) void attn_mfma(
    const _Float16* __restrict__ Kb,
    const _Float16* __restrict__ Qp,
    const _Float16* __restrict__ KTp,
    float* __restrict__ out) {
  const int bid = blockIdx.x;
  const int myid = (bid & 7) * 128 + (bid >> 3);   // 1024 blocks, bijective
  const int bh = myid >> 4;
  const int itile = myid & 15;
  const int b = bh >> 4, h = bh & 15;
  const int tid = threadIdx.x, lane = tid & 63, w = tid >> 6;
  const int l31 = lane & 31;
  const int hi = lane >> 5;
  const int hi8 = hi * 8;
  const int i0 = itile * 128 + w * 32;

  const _Float16* Kh    = Kb + (size_t)b * NTOK * DMODEL + h * HD;
  const _Float16* qsrc  = Qp  + (size_t)bh * 131072 + lane * 8;
  const _Float16* ktsrc = KTp + (size_t)bh * 131072 + lane * 8;

  __shared__ _Float16 QL[2][8][512];   // 16 KB: 8 chunks x 64 lanes x 8 f16
  __shared__ _Float16 KL[2][8][512];   // 16 KB
  __shared__ float lsl[4][32];
  __shared__ float scl[4][32];

  // B-frags of K_i for QK^T (one-time, uncoalesced but tiny)
  f16x8 kbf[4];
#pragma unroll
  for (int ks = 0; ks < 4; ++ks)
    kbf[ks] = *reinterpret_cast<const f16x8*>(
        &Kh[(size_t)(i0 + l31) * DMODEL + ks * 16 + hi8]);

  const f32x16 z16v = Z16;
  f32x16 o0 = z16v, o1 = z16v;
  float mreg = -1e30f, ls = 0.f;

  // prologue: stage tile 0 into buf 0 (each wave stages its 2+2 chunks)
  {
    const int c0 = w * 2, c1 = w * 2 + 1;
    GLDS16(qsrc  + (size_t)c0 * 512, &QL[0][c0][0]);
    GLDS16(qsrc  + (size_t)c1 * 512, &QL[0][c1][0]);
    GLDS16(ktsrc + (size_t)c0 * 512, &KL[0][c0][0]);
    GLDS16(ktsrc + (size_t)c1 * 512, &KL[0][c1][0]);
  }

  for (int jt = 0; jt < 32; ++jt) {
    const int buf = jt & 1;
    __syncthreads();   // drains vmcnt -> buf fully staged; prev reads done
    if (jt + 1 < 32) {
      const int nb = buf ^ 1;
      const size_t tb = (size_t)(jt + 1) * 8 * 512;
      const int c0 = w * 2, c1 = w * 2 + 1;
      GLDS16(qsrc  + tb + (size_t)c0 * 512, &QL[nb][c0][0]);
      GLDS16(qsrc  + tb + (size_t)c1 * 512, &QL[nb][c1][0]);
      GLDS16(ktsrc + tb + (size_t)c0 * 512, &KL[nb][c0][0]);
      GLDS16(ktsrc + tb + (size_t)c1 * 512, &KL[nb][c1][0]);
    }

    // ---- Q fragments from LDS (lane-consecutive 16B, conflict-free) ----
    f16x8 q0[4], q1[4];
#pragma unroll
    for (int ks = 0; ks < 4; ++ks) {
      q0[ks] = *reinterpret_cast<const f16x8*>(&QL[buf][ks][lane * 8]);
      q1[ks] = *reinterpret_cast<const f16x8*>(&QL[buf][4 + ks][lane * 8]);
    }

    // ---- QK^T for both j-halves ----
    f32x16 s0 = z16v, s1 = z16v;
    __builtin_amdgcn_s_setprio(1);
#pragma unroll
    for (int ks = 0; ks < 4; ++ks) {
      s0 = __builtin_amdgcn_mfma_f32_32x32x16_f16(q0[ks], kbf[ks], s0, 0, 0, 0);
      s1 = __builtin_amdgcn_mfma_f32_32x32x16_f16(q1[ks], kbf[ks], s1, 0, 0, 0);
    }
    __builtin_amdgcn_s_setprio(0);

    // ---- KT fragments (issued before softmax; LDS latency hidden) ----
    f16x8 kt0[4], kt1[4];
#pragma unroll
    for (int ks = 0; ks < 4; ++ks) {
      kt0[ks] = *reinterpret_cast<const f16x8*>(&KL[buf][ks][lane * 8]);
      kt1[ks] = *reinterpret_cast<const f16x8*>(&KL[buf][4 + ks][lane * 8]);
    }

    // ---- row max for row i=l31 (32 j's here + 32 in partner half) ----
    float m0 = fmaxf(s0[0], s1[0]);
    float m1 = fmaxf(s0[1], s1[1]);
    float m2 = fmaxf(s0[2], s1[2]);
    float m3 = fmaxf(s0[3], s1[3]);
#pragma unroll
    for (int r = 4; r < 16; r += 4) {
      m0 = fmaxf(m0, fmaxf(s0[r], s1[r]));
      m1 = fmaxf(m1, fmaxf(s0[r + 1], s1[r + 1]));
      m2 = fmaxf(m2, fmaxf(s0[r + 2], s1[r + 2]));
      m3 = fmaxf(m3, fmaxf(s0[r + 3], s1[r + 3]));
    }
    float pm = fmaxf(fmaxf(m0, m1), fmaxf(m2, m3));
    pm = fmaxf(pm, __shfl_xor(pm, 32));

    // ---- defer-max rescale (rare; per-row factor routed via LDS line) ----
    if (!__all(pm <= mreg + 8.0f)) {
      const float mn = fmaxf(mreg, pm);
      const float sc = fexp2(mreg - mn);
      ls *= sc;
      mreg = mn;
      scl[w][l31] = sc;
#pragma unroll
      for (int r = 0; r < 16; ++r) {
        const int il = (r & 3) + 8 * (r >> 2) + 4 * hi;
        const float scr = scl[w][il];
        o0[r] *= scr; o1[r] *= scr;
      }
    }

    // ---- exp2 (scores pre-scaled by log2 e) ----
    float p0a[16], p1a[16];
#pragma unroll
    for (int r = 0; r < 16; ++r) {
      p0a[r] = fexp2(s0[r] - mreg);
      p1a[r] = fexp2(s1[r] - mreg);
    }
    float l0 = 0.f, l1 = 0.f, l2 = 0.f, l3 = 0.f;
#pragma unroll
    for (int r = 0; r < 16; r += 4) {
      l0 += p0a[r]     + p1a[r];
      l1 += p0a[r + 1] + p1a[r + 1];
      l2 += p0a[r + 2] + p1a[r + 2];
      l3 += p0a[r + 3] + p1a[r + 3];
    }
    ls += (l0 + l1) + (l2 + l3);

    // ---- in-register P repack (r4 chain, proven by r4==r5) ----
    f16x8 pfr[4];
    {
      unsigned a0 = pkf16(p0a[0], p0a[1]),  b0 = pkf16(p0a[4], p0a[5]);
      unsigned a1 = pkf16(p0a[2], p0a[3]),  b1 = pkf16(p0a[6], p0a[7]);
      plswap(a0, b0); plswap(a1, b1);
      u32x4 t; t[0] = a0; t[1] = a1; t[2] = b0; t[3] = b1;
      pfr[0] = __builtin_bit_cast(f16x8, t);
      unsigned a2 = pkf16(p0a[8], p0a[9]),   b2 = pkf16(p0a[12], p0a[13]);
      unsigned a3 = pkf16(p0a[10], p0a[11]), b3 = pkf16(p0a[14], p0a[15]);
      plswap(a2, b2); plswap(a3, b3);
      t[0] = a2; t[1] = a3; t[2] = b2; t[3] = b3;
      pfr[1] = __builtin_bit_cast(f16x8, t);
      unsigned a4 = pkf16(p1a[0], p1a[1]),  b4 = pkf16(p1a[4], p1a[5]);
      unsigned a5 = pkf16(p1a[2], p1a[3]),  b5 = pkf16(p1a[6], p1a[7]);
      plswap(a4, b4); plswap(a5, b5);
      t[0] = a4; t[1] = a5; t[2] = b4; t[3] = b5;
      pfr[2] = __builtin_bit_cast(f16x8, t);
      unsigned a6 = pkf16(p1a[8], p1a[9]),   b6 = pkf16(p1a[12], p1a[13]);
      unsigned a7 = pkf16(p1a[10], p1a[11]), b7 = pkf16(p1a[14], p1a[15]);
      plswap(a6, b6); plswap(a7, b7);
      t[0] = a6; t[1] = a7; t[2] = b6; t[3] = b7;
      pfr[3] = __builtin_bit_cast(f16x8, t);
    }

    // ---- PV ----
    __builtin_amdgcn_s_setprio(1);
#pragma unroll
    for (int ks = 0; ks < 4; ++ks) {
      o0 = __builtin_amdgcn_mfma_f32_32x32x16_f16(pfr[ks], kt0[ks], o0, 0, 0, 0);
      o1 = __builtin_amdgcn_mfma_f32_32x32x16_f16(pfr[ks], kt1[ks], o1, 0, 0, 0);
    }
    __builtin_amdgcn_s_setprio(0);
  }

  // ---- finalize: combine lsum across lane halves, divide, store ----
  lsl[w][l31] = ls + __shfl_xor(ls, 32);
  __syncthreads();
#pragma unroll
  for (int r = 0; r < 16; ++r) {
    const int il = (r & 3) + 8 * (r >> 2) + 4 * hi;
    const float inv = 1.0f / lsl[w][il];
    const size_t rowb = ((size_t)bh * NTOK + i0 + il) * HD;
    out[rowb + l31]      = o0[r] * inv;
    out[rowb + 32 + l31] = o1[r] * inv;
  }
}

extern "C" void kernel_launch(void* const* d_in, const int* in_sizes, int n_in,
                              void* d_out, int out_size, void* d_ws, size_t ws_size,
                              hipStream_t stream) {
  const float* x  = (const float*)d_in[0];
  const float* Wk = (const float*)d_in[1];
  const float* Wq = (const float*)d_in[2];
  // d_in[3] (Wv) is dead code in the reference — never read.
  float* out = (float*)d_out;

  // ws (f16 elems): [xb|Qp: 8388608][Wkb: 1048576][Wqb: 1048576]
  //                 [Kb: 8388608][Qb|KTp: 8388608]
  _Float16* xb  = (_Float16*)d_ws;
  _Float16* Qp  = xb;
  _Float16* Wkb = xb + (size_t)8388608;
  _Float16* Wqb = Wkb + (size_t)1048576;
  _Float16* Kb  = Wqb + (size_t)1048576;
  _Float16* Qb  = Kb + (size_t)8388608;
  _Float16* KTp = Qb;

  cvt_f32_f16<<<8192, 256, 0, stream>>>(x, xb, 2097152, 1.0f);
  cvt_w<<<dim3(1024, 2), 256, 0, stream>>>(Wk, Wq, Wkb, Wqb);

  dim3 ggrid(MROWS / 128, DMODEL / 128, 2);
  gemm_f16<<<ggrid, 256, 0, stream>>>(xb, Wkb, Wqb, Kb, Qb);

  pack_qkt<<<dim3(2048, 2), 256, 0, stream>>>(Qb, Kb, Qp, KTp);

  attn_mfma<<<1024, 256, 0, stream>>>(Kb, Qp, KTp, out);
}

// Round 12
// 184.364 us; speedup vs baseline: 1.1432x; 1.0274x over previous
//
#include <hip/hip_runtime.h>
#include <cstdint>
#include <cstddef>

#define NTOK 2048
#define DMODEL 1024
#define HD 64
#define MROWS 8192

using f16x8  = __attribute__((ext_vector_type(8))) _Float16;
using f16x4  = __attribute__((ext_vector_type(4))) _Float16;
using f32x4  = __attribute__((ext_vector_type(4))) float;
using f32x16 = __attribute__((ext_vector_type(16))) float;
using u16x8  = __attribute__((ext_vector_type(8))) unsigned short;
using u32x4  = __attribute__((ext_vector_type(4))) unsigned int;

#define Z16 {0.f,0.f,0.f,0.f,0.f,0.f,0.f,0.f,0.f,0.f,0.f,0.f,0.f,0.f,0.f,0.f}

__device__ __forceinline__ unsigned pkf16(float a, float b) {
  return __builtin_bit_cast(unsigned, __builtin_amdgcn_cvt_pkrtz(a, b));
}
__device__ __forceinline__ void plswap(unsigned &a, unsigned &b) {
  auto r = __builtin_amdgcn_permlane32_swap(a, b, false, false);
  a = r[0]; b = r[1];
}
// raw v_exp_f32: args always <= 0; flush-to-zero below -126 is correct for
// softmax tails.
__device__ __forceinline__ float fexp2(float x) {
  return __builtin_amdgcn_exp2f(x);
}

// ---------------------------------------------------------------------------
// f32 -> f16 convert (x)
// ---------------------------------------------------------------------------
__global__ __launch_bounds__(256) void cvt_f32_f16(const float* __restrict__ in,
                                                   _Float16* __restrict__ out,
                                                   int n4, float scale) {
  int idx = blockIdx.x * 256 + threadIdx.x;
  if (idx < n4) {
    float4 v = reinterpret_cast<const float4*>(in)[idx];
    f16x4 o;
    o.x = (_Float16)(v.x * scale); o.y = (_Float16)(v.y * scale);
    o.z = (_Float16)(v.z * scale); o.w = (_Float16)(v.w * scale);
    reinterpret_cast<f16x4*>(out)[idx] = o;
  }
}

// both weight matrices in one launch; log2(e) folded into Wq
__global__ __launch_bounds__(256) void cvt_w(const float* __restrict__ Wk,
                                             const float* __restrict__ Wq,
                                             _Float16* __restrict__ Wkb,
                                             _Float16* __restrict__ Wqb) {
  const int idx = blockIdx.x * 256 + threadIdx.x;
  const float* in = blockIdx.y ? Wq : Wk;
  _Float16* out = blockIdx.y ? Wqb : Wkb;
  const float scale = blockIdx.y ? 1.4426950408889634f : 1.0f;
  float4 v = reinterpret_cast<const float4*>(in)[idx];
  f16x4 o;
  o.x = (_Float16)(v.x * scale); o.y = (_Float16)(v.y * scale);
  o.z = (_Float16)(v.z * scale); o.w = (_Float16)(v.w * scale);
  reinterpret_cast<f16x4*>(out)[idx] = o;
}

// ---------------------------------------------------------------------------
// f16 MFMA GEMM: Y[m][o] = sum_k X[m][k] * W[o][k]  (NT), Y stored f16.
// ---------------------------------------------------------------------------
#define GLDS16(g, l) __builtin_amdgcn_global_load_lds(                      \
    (const __attribute__((address_space(1))) void*)(g),                     \
    (__attribute__((address_space(3))) void*)(l), 16, 0, 0)

__global__ __launch_bounds__(256) void gemm_f16(
    const _Float16* __restrict__ X,
    const _Float16* __restrict__ Wk,
    const _Float16* __restrict__ Wq,
    _Float16* __restrict__ Kb,
    _Float16* __restrict__ Qb) {
  const _Float16* __restrict__ W = blockIdx.z ? Wq : Wk;
  _Float16* __restrict__ Y = blockIdx.z ? Qb : Kb;

  __shared__ _Float16 As[2][128 * 32];
  __shared__ _Float16 Bs[2][128 * 32];

  const int tid = threadIdx.x;
  const int lane = tid & 63;
  const int w = tid >> 6;
  const int m0 = blockIdx.x * 128;
  const int o0 = blockIdx.y * 128;

  const int srow = w * 32 + (lane >> 2);
  const int scol = (lane & 3) * 8;
  const _Float16* xsrc = X + (size_t)(m0 + srow) * DMODEL + scol;
  const _Float16* wsrc = W + (size_t)(o0 + srow) * DMODEL + scol;

  const int wr = w >> 1, wc = w & 1;
  const int arow = lane & 15, kg = lane >> 4;

  f32x4 zero = {0.f, 0.f, 0.f, 0.f};
  f32x4 acc[4][4];
#pragma unroll
  for (int mi = 0; mi < 4; ++mi)
#pragma unroll
    for (int ni = 0; ni < 4; ++ni) acc[mi][ni] = zero;

  GLDS16(xsrc,               &As[0][(w * 32) * 32]);
  GLDS16(xsrc + 16 * DMODEL, &As[0][(w * 32 + 16) * 32]);
  GLDS16(wsrc,               &Bs[0][(w * 32) * 32]);
  GLDS16(wsrc + 16 * DMODEL, &Bs[0][(w * 32 + 16) * 32]);

  for (int kt = 0; kt < 32; ++kt) {
    __syncthreads();
    if (kt + 1 < 32) {
      const int ko = (kt + 1) * 32;
      const int bn = (kt + 1) & 1;
      GLDS16(xsrc + ko,               &As[bn][(w * 32) * 32]);
      GLDS16(xsrc + ko + 16 * DMODEL, &As[bn][(w * 32 + 16) * 32]);
      GLDS16(wsrc + ko,               &Bs[bn][(w * 32) * 32]);
      GLDS16(wsrc + ko + 16 * DMODEL, &Bs[bn][(w * 32 + 16) * 32]);
    }
    const int buf = kt & 1;
    f16x8 af[4], bfr[4];
#pragma unroll
    for (int mi = 0; mi < 4; ++mi)
      af[mi] = *reinterpret_cast<const f16x8*>(
          &As[buf][(wr * 64 + mi * 16 + arow) * 32 + kg * 8]);
#pragma unroll
    for (int ni = 0; ni < 4; ++ni)
      bfr[ni] = *reinterpret_cast<const f16x8*>(
          &Bs[buf][(wc * 64 + ni * 16 + arow) * 32 + kg * 8]);
#pragma unroll
    for (int mi = 0; mi < 4; ++mi)
#pragma unroll
      for (int ni = 0; ni < 4; ++ni)
        acc[mi][ni] = __builtin_amdgcn_mfma_f32_16x16x32_f16(
            af[mi], bfr[ni], acc[mi][ni], 0, 0, 0);
  }

#pragma unroll
  for (int mi = 0; mi < 4; ++mi) {
#pragma unroll
    for (int ni = 0; ni < 4; ++ni) {
#pragma unroll
      for (int r = 0; r < 4; ++r) {
        const int m = m0 + wr * 64 + mi * 16 + kg * 4 + r;
        const int o = o0 + wc * 64 + ni * 16 + arow;
        Y[(size_t)m * DMODEL + o] = (_Float16)acc[mi][ni][r];
      }
    }
  }
}

// ---------------------------------------------------------------------------
// Combined pack kernel (grid.y: 0 = pack Q rows, 1 = pack K transposed).
// y=0: Qp[bh][rt(32-row tiles)][ks][lane][8]  = Q_head[rt*32+(l&31)][ks*16+(l>>5)*8+e]
// y=1: KTp[bh][jt][ds][ks][lane][8] = K_head[jt*64+ks*16+(l>>5)*8+e][ds*32+(l&31)]
// ---------------------------------------------------------------------------
__global__ __launch_bounds__(256) void pack_qkt(
    const _Float16* __restrict__ Qb,
    const _Float16* __restrict__ Kb,
    _Float16* __restrict__ Qp,
    _Float16* __restrict__ KTp) {
  const int blk = blockIdx.x;
  const int bh = blk >> 5;
  const int t64 = blk & 31;
  const int b = bh >> 4, h = bh & 15;
  const int tid = threadIdx.x;
  const _Float16* Src = blockIdx.y ? Kb : Qb;

  __shared__ _Float16 t[64][72];
#pragma unroll
  for (int rr = 0; rr < 2; ++rr) {
    const int c = tid + rr * 256;
    const int jr = c >> 3, dcol = (c & 7) * 8;
    *reinterpret_cast<f16x8*>(&t[jr][dcol]) =
        *reinterpret_cast<const f16x8*>(
            &Src[(size_t)(b * NTOK + t64 * 64 + jr) * DMODEL + h * HD + dcol]);
  }
  __syncthreads();
  if (blockIdx.y == 0) {
#pragma unroll
    for (int rr = 0; rr < 2; ++rr) {
      const int cI = tid + rr * 256;   // (rs,ks,l)
      const int rs = cI >> 8, ks = (cI >> 6) & 3, l = cI & 63;
      f16x8 v = *reinterpret_cast<const f16x8*>(
          &t[rs * 32 + (l & 31)][ks * 16 + (l >> 5) * 8]);
      const size_t ch = ((size_t)(bh * 64 + t64 * 2 + rs) * 4 + ks) * 512 + l * 8;
      *reinterpret_cast<f16x8*>(&Qp[ch]) = v;
    }
  } else {
#pragma unroll
    for (int rr = 0; rr < 2; ++rr) {
      const int cI = tid + rr * 256;   // (ds,ks,l)
      const int ds = cI >> 8, ks = (cI >> 6) & 3, l = cI & 63;
      const int col = ds * 32 + (l & 31);
      const int row0 = ks * 16 + (l >> 5) * 8;
      f16x8 v;
#pragma unroll
      for (int e = 0; e < 8; ++e) v[e] = t[row0 + e][col];
      const size_t ch = (((size_t)(bh * 32 + t64) * 2 + ds) * 4 + ks) * 512 + l * 8;
      *reinterpret_cast<f16x8*>(&KTp[ch]) = v;
    }
  }
}

// ---------------------------------------------------------------------------
// Swapped-operand MFMA flash attention, j-tile=32, minimal register
// footprint (r11 lesson: occupancy was capped ~2 waves/SIMD by the unified
// VGPR+AGPR budget, not by VGPR_Count=124 — s0/s1 + ping-pong prefetch +
// p-arrays cost a 3rd resident wave; TLP is the cheapest latency hider).
// Changes vs r9: single f32x16 S per tile (j-tile 32), exp2 IN-PLACE on S,
// no explicit multi-tile prefetch (was +2%), __launch_bounds__(256,3).
// Per tile: S = mfma(Q, kbf) [col=i]; row-max + shfl_xor(32); defer-max
// THR=8 with per-row rescale via LDS scl line; S <- exp2(S-m); repack to
// pfr[2] (cvt_pkrtz+permlane32_swap, r4-verified chain); O += mfma(P, KT).
// ---------------------------------------------------------------------------
__global__ __launch_bounds__(256, 3) void attn_mfma(
    const _Float16* __restrict__ Kb,
    const _Float16* __restrict__ Qp,
    const _Float16* __restrict__ KTp,
    float* __restrict__ out) {
  const int bid = blockIdx.x;
  const int myid = (bid & 7) * 128 + (bid >> 3);   // 1024 blocks, bijective
  const int bh = myid >> 4;
  const int itile = myid & 15;
  const int b = bh >> 4, h = bh & 15;
  const int tid = threadIdx.x, lane = tid & 63, w = tid >> 6;
  const int l31 = lane & 31;
  const int hi = lane >> 5;
  const int hi8 = hi * 8;
  const int i0 = itile * 128 + w * 32;

  const _Float16* Kh   = Kb + (size_t)b * NTOK * DMODEL + h * HD;
  const _Float16* qpp  = Qp  + (size_t)bh * 131072 + lane * 8;
  const _Float16* ktpp = KTp + (size_t)bh * 131072 + lane * 8;

  __shared__ float lsl[4][32];
  __shared__ float scl[4][32];

  // B-frags of K_i for QK^T (one-time, uncoalesced but tiny)
  f16x8 kbf[4];
#pragma unroll
  for (int ks = 0; ks < 4; ++ks)
    kbf[ks] = *reinterpret_cast<const f16x8*>(
        &Kh[(size_t)(i0 + l31) * DMODEL + ks * 16 + hi8]);

  const f32x16 z16v = Z16;
  f32x16 o0 = z16v, o1 = z16v;
  float mreg = -1e30f, ls = 0.f;

  for (int jt = 0; jt < 64; ++jt) {
    // ---- Q fragments for this 32-j tile ----
    f16x8 q[4];
#pragma unroll
    for (int ks = 0; ks < 4; ++ks)
      q[ks] = *reinterpret_cast<const f16x8*>(qpp + ((size_t)jt * 4 + ks) * 512);

    // ---- QK^T: S^T(32j x 32i), lane holds col i=l31, 16 j's in regs ----
    f32x16 s = z16v;
    __builtin_amdgcn_s_setprio(1);
#pragma unroll
    for (int ks = 0; ks < 4; ++ks)
      s = __builtin_amdgcn_mfma_f32_32x32x16_f16(q[ks], kbf[ks], s, 0, 0, 0);
    __builtin_amdgcn_s_setprio(0);

    // ---- KT fragments (independent of softmax; latency hidden under it) ----
    f16x8 kt0[2], kt1[2];
    {
      const size_t base = ((size_t)(jt >> 1) * 8 + (size_t)(jt & 1) * 2) * 512;
#pragma unroll
      for (int kk = 0; kk < 2; ++kk) {
        kt0[kk] = *reinterpret_cast<const f16x8*>(ktpp + base + (size_t)kk * 512);
        kt1[kk] = *reinterpret_cast<const f16x8*>(ktpp + base + (size_t)(4 + kk) * 512);
      }
    }

    // ---- row max (16 j's here + 16 in partner half) ----
    float m0 = fmaxf(s[0], s[4]);
    float m1 = fmaxf(s[1], s[5]);
    float m2 = fmaxf(s[2], s[6]);
    float m3 = fmaxf(s[3], s[7]);
#pragma unroll
    for (int r = 8; r < 16; r += 4) {
      m0 = fmaxf(m0, s[r]);
      m1 = fmaxf(m1, s[r + 1]);
      m2 = fmaxf(m2, s[r + 2]);
      m3 = fmaxf(m3, s[r + 3]);
    }
    float pm = fmaxf(fmaxf(m0, m1), fmaxf(m2, m3));
    pm = fmaxf(pm, __shfl_xor(pm, 32));

    // ---- defer-max rescale (rare; per-row factor routed via LDS line) ----
    if (!__all(pm <= mreg + 8.0f)) {
      const float mn = fmaxf(mreg, pm);
      const float sc = fexp2(mreg - mn);
      ls *= sc;
      mreg = mn;
      scl[w][l31] = sc;
#pragma unroll
      for (int r = 0; r < 16; ++r) {
        const int il = (r & 3) + 8 * (r >> 2) + 4 * hi;
        const float scr = scl[w][il];
        o0[r] *= scr; o1[r] *= scr;
      }
    }

    // ---- exp2 in place (scores pre-scaled by log2 e) ----
#pragma unroll
    for (int r = 0; r < 16; ++r) s[r] = fexp2(s[r] - mreg);
    {
      float l0 = (s[0] + s[4]) + (s[8] + s[12]);
      float l1 = (s[1] + s[5]) + (s[9] + s[13]);
      float l2 = (s[2] + s[6]) + (s[10] + s[14]);
      float l3 = (s[3] + s[7]) + (s[11] + s[15]);
      ls += (l0 + l1) + (l2 + l3);
    }

    // ---- in-register P repack (r4 chain, proven by r4==r5) ----
    f16x8 pfr[2];
    {
      unsigned a0 = pkf16(s[0], s[1]),  b0 = pkf16(s[4], s[5]);
      unsigned a1 = pkf16(s[2], s[3]),  b1 = pkf16(s[6], s[7]);
      plswap(a0, b0); plswap(a1, b1);
      u32x4 t; t[0] = a0; t[1] = a1; t[2] = b0; t[3] = b1;
      pfr[0] = __builtin_bit_cast(f16x8, t);
      unsigned a2 = pkf16(s[8], s[9]),   b2 = pkf16(s[12], s[13]);
      unsigned a3 = pkf16(s[10], s[11]), b3 = pkf16(s[14], s[15]);
      plswap(a2, b2); plswap(a3, b3);
      t[0] = a2; t[1] = a3; t[2] = b2; t[3] = b3;
      pfr[1] = __builtin_bit_cast(f16x8, t);
    }

    // ---- PV ----
    __builtin_amdgcn_s_setprio(1);
#pragma unroll
    for (int kk = 0; kk < 2; ++kk) {
      o0 = __builtin_amdgcn_mfma_f32_32x32x16_f16(pfr[kk], kt0[kk], o0, 0, 0, 0);
      o1 = __builtin_amdgcn_mfma_f32_32x32x16_f16(pfr[kk], kt1[kk], o1, 0, 0, 0);
    }
    __builtin_amdgcn_s_setprio(0);
  }

  // ---- finalize: combine lsum across lane halves, divide, store ----
  lsl[w][l31] = ls + __shfl_xor(ls, 32);
  __syncthreads();
#pragma unroll
  for (int r = 0; r < 16; ++r) {
    const int il = (r & 3) + 8 * (r >> 2) + 4 * hi;
    const float inv = 1.0f / lsl[w][il];
    const size_t rowb = ((size_t)bh * NTOK + i0 + il) * HD;
    out[rowb + l31]      = o0[r] * inv;
    out[rowb + 32 + l31] = o1[r] * inv;
  }
}

extern "C" void kernel_launch(void* const* d_in, const int* in_sizes, int n_in,
                              void* d_out, int out_size, void* d_ws, size_t ws_size,
                              hipStream_t stream) {
  const float* x  = (const float*)d_in[0];
  const float* Wk = (const float*)d_in[1];
  const float* Wq = (const float*)d_in[2];
  // d_in[3] (Wv) is dead code in the reference — never read.
  float* out = (float*)d_out;

  // ws (f16 elems): [xb|Qp: 8388608][Wkb: 1048576][Wqb: 1048576]
  //                 [Kb: 8388608][Qb|KTp: 8388608]
  _Float16* xb  = (_Float16*)d_ws;
  _Float16* Qp  = xb;
  _Float16* Wkb = xb + (size_t)8388608;
  _Float16* Wqb = Wkb + (size_t)1048576;
  _Float16* Kb  = Wqb + (size_t)1048576;
  _Float16* Qb  = Kb + (size_t)8388608;
  _Float16* KTp = Qb;

  cvt_f32_f16<<<8192, 256, 0, stream>>>(x, xb, 2097152, 1.0f);
  cvt_w<<<dim3(1024, 2), 256, 0, stream>>>(Wk, Wq, Wkb, Wqb);

  dim3 ggrid(MROWS / 128, DMODEL / 128, 2);
  gemm_f16<<<ggrid, 256, 0, stream>>>(xb, Wkb, Wqb, Kb, Qb);

  pack_qkt<<<dim3(2048, 2), 256, 0, stream>>>(Qb, Kb, Qp, KTp);

  attn_mfma<<<1024, 256, 0, stream>>>(Kb, Qp, KTp, out);
}